// Round 4
// baseline (477.181 us; speedup 1.0000x reference)
//
#include <hip/hip_runtime.h>

// B=32, S=2048, F=768, H=8  — all fp32
// ws layout (floats): att/w [B*H*S]=524288 | gate [524288] | pooled [B*F*H]=196608

__global__ __launch_bounds__(256) void kLogits(const float* __restrict__ x,
    const float* __restrict__ Wa, const float* __restrict__ ba,
    const float* __restrict__ Wg, const float* __restrict__ bg,
    float* __restrict__ att, float* __restrict__ gate)
{
    __shared__ float Wl[16 * 768];   // rows 0..7 = W_att, 8..15 = W_gate
    int t = threadIdx.x;
    for (int i = t; i < 12288; i += 256)
        Wl[i] = (i < 6144) ? Wa[i] : Wg[i - 6144];
    __syncthreads();

    int wid = t >> 6, lane = t & 63;
    long row0 = (long)blockIdx.x * 8 + wid * 2;   // each wave: 2 rows

    float4 xv[2][3];
    #pragma unroll
    for (int r = 0; r < 2; r++) {
        const float4* xp = reinterpret_cast<const float4*>(x + (row0 + r) * 768 + lane * 4);
        #pragma unroll
        for (int k = 0; k < 3; k++) xv[r][k] = xp[k * 64];
    }

    float acc[16][2];
    #pragma unroll
    for (int h = 0; h < 16; h++) { acc[h][0] = 0.f; acc[h][1] = 0.f; }

    #pragma unroll
    for (int h = 0; h < 16; h++) {
        const float4* wp = reinterpret_cast<const float4*>(&Wl[h * 768 + lane * 4]);
        #pragma unroll
        for (int k = 0; k < 3; k++) {
            float4 wv = wp[k * 64];
            #pragma unroll
            for (int r = 0; r < 2; r++) {
                acc[h][r] += wv.x * xv[r][k].x;
                acc[h][r] += wv.y * xv[r][k].y;
                acc[h][r] += wv.z * xv[r][k].z;
                acc[h][r] += wv.w * xv[r][k].w;
            }
        }
    }

    #pragma unroll
    for (int off = 1; off < 64; off <<= 1) {
        #pragma unroll
        for (int h = 0; h < 16; h++) {
            acc[h][0] += __shfl_xor(acc[h][0], off, 64);
            acc[h][1] += __shfl_xor(acc[h][1], off, 64);
        }
    }

    int b = (int)(row0 >> 11);
    if (lane < 8) {
        float bias = ba[lane];
        #pragma unroll
        for (int r = 0; r < 2; r++) {
            int s = (int)((row0 + r) & 2047);
            att[((b << 3) + lane) * 2048 + s] = acc[lane][r] + bias;
        }
    } else if (lane < 16) {
        int h = lane - 8;
        float bias = bg[h];
        #pragma unroll
        for (int r = 0; r < 2; r++) {
            int s = (int)((row0 + r) & 2047);
            float g = acc[lane][r] + bias;
            gate[((b << 3) + h) * 2048 + s] = 1.f / (1.f + __expf(-g));
        }
    }
}

// block per (b,h): softmax over S, fold in sigmoid(gate), write w in place of att
__global__ __launch_bounds__(256) void kSoftmax(float* __restrict__ att,
                                                const float* __restrict__ gate)
{
    int bh = blockIdx.x;
    int t = threadIdx.x;
    long base = (long)bh * 2048;

    float v[8];
    #pragma unroll
    for (int i = 0; i < 8; i++) v[i] = att[base + t + (i << 8)];

    float m = v[0];
    #pragma unroll
    for (int i = 1; i < 8; i++) m = fmaxf(m, v[i]);
    #pragma unroll
    for (int off = 1; off < 64; off <<= 1) m = fmaxf(m, __shfl_xor(m, off, 64));

    __shared__ float sm[4], ssum[4];
    int wid = t >> 6, lane = t & 63;
    if (lane == 0) sm[wid] = m;
    __syncthreads();
    float M = fmaxf(fmaxf(sm[0], sm[1]), fmaxf(sm[2], sm[3]));

    float e[8]; float s = 0.f;
    #pragma unroll
    for (int i = 0; i < 8; i++) { e[i] = __expf(v[i] - M); s += e[i]; }
    #pragma unroll
    for (int off = 1; off < 64; off <<= 1) s += __shfl_xor(s, off, 64);
    if (lane == 0) ssum[wid] = s;
    __syncthreads();
    float inv = 1.f / (ssum[0] + ssum[1] + ssum[2] + ssum[3]);

    #pragma unroll
    for (int i = 0; i < 8; i++) {
        long idx = base + t + (i << 8);
        att[idx] = e[i] * inv * gate[idx];
    }
}

// block per (s-chunk=128, b): pooled[b,f,h] += sum_s w[b,h,s]*x[b,s,f]
__global__ __launch_bounds__(256) void kPool(const float* __restrict__ x,
                                             const float* __restrict__ w,
                                             float* __restrict__ pooled)
{
    int sc = blockIdx.x, b = blockIdx.y;
    int s0 = sc << 7;
    __shared__ float wl[8 * 128];
    int t = threadIdx.x;
    for (int i = t; i < 1024; i += 256) {
        int h = i >> 7, ss = i & 127;
        wl[i] = w[((long)((b << 3) + h) << 11) + s0 + ss];
    }
    __syncthreads();

    float acc[8][3];
    #pragma unroll
    for (int h = 0; h < 8; h++)
        #pragma unroll
        for (int j = 0; j < 3; j++) acc[h][j] = 0.f;

    const float* xb = x + ((long)(b << 11) + s0) * 768 + t;
    #pragma unroll 2
    for (int ss = 0; ss < 128; ss++) {
        float x0 = xb[0], x1 = xb[256], x2 = xb[512];
        #pragma unroll
        for (int h = 0; h < 8; h++) {
            float wv = wl[(h << 7) + ss];
            acc[h][0] += wv * x0;
            acc[h][1] += wv * x1;
            acc[h][2] += wv * x2;
        }
        xb += 768;
    }

    #pragma unroll
    for (int j = 0; j < 3; j++) {
        float* pp = pooled + b * 6144 + (t + (j << 8)) * 8;
        #pragma unroll
        for (int h = 0; h < 8; h++) atomicAdd(pp + h, acc[h][j]);
    }
}

__global__ __launch_bounds__(256) void kOutInit(const float* __restrict__ bo,
                                                float* __restrict__ out)
{
    int idx = blockIdx.x * 256 + threadIdx.x;   // 24576 total
    out[idx] = bo[idx % 768];
}

// out[b,fo] += sum_k pooled[b,k]*Wout[fo,k]; block = (k-chunk 256, fo-chunk 16)
__global__ __launch_bounds__(256) void kGemm(const float* __restrict__ pooled,
                                             const float* __restrict__ Wout,
                                             float* __restrict__ out)
{
    int kg = blockIdx.x, fg = blockIdx.y;
    int k0 = kg << 8, fo0 = fg << 4;
    __shared__ float pl[32 * 258];   // +2 pad: float2-aligned, 2-way conflicts free
    __shared__ float wl[16 * 258];
    int t = threadIdx.x;
    #pragma unroll 4
    for (int i = 0; i < 32; i++) pl[i * 258 + t] = pooled[i * 6144 + k0 + t];
    #pragma unroll 4
    for (int j = 0; j < 16; j++) wl[j * 258 + t] = Wout[(fo0 + j) * 6144 + k0 + t];
    __syncthreads();

    int b = t & 31, fq = t >> 5;
    const float2* pp = reinterpret_cast<const float2*>(pl + b * 258);
    const float2* u  = reinterpret_cast<const float2*>(wl + fq * 258);
    const float2* vv = reinterpret_cast<const float2*>(wl + (fq + 8) * 258);
    float a0 = 0.f, a1 = 0.f;
    #pragma unroll 8
    for (int kk = 0; kk < 128; kk++) {
        float2 p = pp[kk], w0 = u[kk], w1 = vv[kk];
        a0 += p.x * w0.x + p.y * w0.y;
        a1 += p.x * w1.x + p.y * w1.y;
    }
    atomicAdd(&out[b * 768 + fo0 + fq], a0);
    atomicAdd(&out[b * 768 + fo0 + 8 + fq], a1);
}

extern "C" void kernel_launch(void* const* d_in, const int* in_sizes, int n_in,
                              void* d_out, int out_size, void* d_ws, size_t ws_size,
                              hipStream_t stream)
{
    const float* x  = (const float*)d_in[0];
    const float* Wa = (const float*)d_in[1];
    const float* ba = (const float*)d_in[2];
    const float* Wg = (const float*)d_in[3];
    const float* bg = (const float*)d_in[4];
    const float* Wo = (const float*)d_in[5];
    const float* bo = (const float*)d_in[6];
    float* out = (float*)d_out;

    float* att    = (float*)d_ws;          // 524288 floats (becomes w in place)
    float* gate   = att + 524288;          // 524288 floats
    float* pooled = gate + 524288;         // 196608 floats

    hipMemsetAsync(pooled, 0, 196608 * sizeof(float), stream);

    kLogits <<<8192,          256, 0, stream>>>(x, Wa, ba, Wg, bg, att, gate);
    kSoftmax<<<256,           256, 0, stream>>>(att, gate);
    kPool   <<<dim3(16, 32),  256, 0, stream>>>(x, att, pooled);
    kOutInit<<<96,            256, 0, stream>>>(bo, out);
    kGemm   <<<dim3(24, 48),  256, 0, stream>>>(pooled, Wo, out);
}